// Round 10
// baseline (250.019 us; speedup 1.0000x reference)
//
#include <hip/hip_runtime.h>
#include <stdint.h>

#define BDIM 4
#define TDIM 4096
#define CDIM 1024
#define MDIM (BDIM * TDIM) // 16384
#define SSEG 64            // segments along T
#define LSEG 64            // steps per segment
#define NCH  (BDIM * CDIM) // 4096 channels

#define GK   1024          // GEMM K
#define GK2  2048          // K row stride in bytes (bf16)
#define NTK  16            // K-tiles of 64

typedef __attribute__((ext_vector_type(8))) short bf16x8;
typedef __attribute__((ext_vector_type(4))) float f32x4;

__device__ __forceinline__ unsigned short f2bf(float f) {
    unsigned u = __builtin_bit_cast(unsigned, f);
    u = u + 0x7fffu + ((u >> 16) & 1u); // RNE
    return (unsigned short)(u >> 16);
}
__device__ __forceinline__ float bf2f(unsigned short h) {
    unsigned u = ((unsigned)h) << 16;
    return __builtin_bit_cast(float, u);
}

typedef __attribute__((address_space(1))) const unsigned int g_u32;
typedef __attribute__((address_space(3))) unsigned int l_u32;
__device__ __forceinline__ void gload_lds16(const void* g, void* l) {
    __builtin_amdgcn_global_load_lds((g_u32*)g, (l_u32*)l, 16, 0, 0);
}

// ---------------- fp32 -> bf16 cast (vectorized) ----------------
__global__ void castk(const float* __restrict__ src, unsigned short* __restrict__ dst, int n4) {
    int i = blockIdx.x * blockDim.x + threadIdx.x;
    int stride = gridDim.x * blockDim.x;
    for (int j = i; j < n4; j += stride) {
        float4 f = ((const float4*)src)[j];
        ushort4 o;
        o.x = f2bf(f.x); o.y = f2bf(f.y); o.z = f2bf(f.z); o.w = f2bf(f.w);
        ((ushort4*)dst)[j] = o;
    }
}

// all 4 weight matrices in one launch
__global__ void castw(const float* __restrict__ kw, const float* __restrict__ vw,
                      const float* __restrict__ rw, const float* __restrict__ ow,
                      unsigned short* __restrict__ wf, unsigned short* __restrict__ owb) {
    int i = blockIdx.x * 256 + threadIdx.x;
    int m = i >> 18, j = i & 262143;
    const float* s = (m == 0) ? kw : (m == 1) ? vw : (m == 2) ? rw : ow;
    unsigned short* d = (m < 3) ? (wf + (size_t)m * 1048576) : owb;
    float4 f = ((const float4*)s)[j];
    ushort4 o;
    o.x = f2bf(f.x); o.y = f2bf(f.y); o.z = f2bf(f.z); o.w = f2bf(f.w);
    ((ushort4*)d)[j] = o;
}

// ---------------- 256x256 8-phase bf16 GEMM (Y = A * Bw^T) ----------------
// Round-5 verified skeleton (16x16x32 MFMA, 1 half-tile staged per phase,
// counted vmcnt, intrinsic barriers, XOR swizzle both-sides, 0 conflicts).
// NEW: NP projections per block (p-loop re-running the K-loop against
// B-panels p*1024.. with the SAME A-panel -> grid 256 = 1 block/CU, 1 round).
// vmcnt ledger verified at p-seam: prologue vmcnt(4) after 12 loads drains
// epilogue stores + leaves tile0's 8 loads resident.
// MODE 0: fused QKV epilogue -> oK/oV(bf16), oR(sigmoid,bf16). MODE 1: fp32.
template <int MODE, int NT, int NP>
__global__ __launch_bounds__(512, 2) void gemm256(
    const unsigned short* __restrict__ A,
    const unsigned short* __restrict__ Bw,
    unsigned short* __restrict__ oK, unsigned short* __restrict__ oV,
    unsigned short* __restrict__ oR, float* __restrict__ oF)
{
    extern __shared__ char sh[];
    char* shA = sh;             // 2 slots x 2 halves x 16384 B
    char* shB = sh + 65536;

    const int tid  = threadIdx.x;
    const int wave = tid >> 6;
    const int lane = tid & 63;
    const int wm   = wave >> 2;      // 0..1 (M half)
    const int wn   = wave & 3;       // 0..3 (N quarter)
    const int lrow = lane & 15;
    const int koct = lane >> 4;      // 0..3

    // per-thread-constant swizzled k-offsets for LDS reads
    const int kb0 = (koct * 16) ^ ((lrow & 7) << 4);
    const int kb1 = kb0 ^ 64;

    // per-thread-constant stage offsets (2 chunks of 16B per stage call)
    const int sr0  = tid >> 3;                 // row of chunk 0 (0..63)
    const int sc0  = ((tid & 7) * 16) ^ ((sr0 & 7) << 4);
    const int sr1  = (512 + tid) >> 3;         // row of chunk 1 (64..127)
    const int sc1  = ((tid & 7) * 16) ^ ((sr1 & 7) << 4);
    const int sd0  = tid * 16;
    const int sd1  = 8192 + tid * 16;

    // L2-locality XCD swizzle (grid = 8 * 8 * NT blocks)
    const int bid = blockIdx.x;
    const int xcd = bid & 7;
    const int idx = bid >> 3;
    const int mt  = xcd * 8 + idx / NT;  // disjoint A-slice per XCD
    const int nt  = idx % NT;            // nt-fast: A panel L2-reused
    const size_t row0 = (size_t)mt * 256;
    const size_t colb = (size_t)nt * 256;       // channel base within region

    const char* gA = (const char*)A + row0 * GK2;

    for (int p = 0; p < NP; ++p) {
        // B rows for this projection region
        const char* gB = (const char*)Bw + ((size_t)p * 1024 + colb) * GK2;

        // stage one half-tile of tile tt; part: 0=A h0, 1=A h1, 2=B h0, 3=B h1
        auto stage = [&](int tt, int part) {
            if (tt >= NTK) return;
            int slot = tt & 1;
            int isA  = (part < 2) ? 1 : 0;
            int half = part & 1;
            const char* gbase = (isA ? gA : gB) + (size_t)half * 128 * GK2 + tt * 128;
            char* lbase = (isA ? shA : shB) + (slot * 2 + half) * 16384;
            gload_lds16(gbase + (size_t)sr0 * GK2 + sc0, lbase + sd0);
            gload_lds16(gbase + (size_t)sr1 * GK2 + sc1, lbase + sd1);
        };

        __builtin_amdgcn_s_barrier();   // all waves done with prior p's LDS

        // prologue: tile0 (A0,A1,B0,B1) + tile1 (A0,A1) = 6 halves (12 loads)
        stage(0, 0); stage(0, 1); stage(0, 2); stage(0, 3);
        stage(1, 0); stage(1, 1);
        asm volatile("s_waitcnt vmcnt(4)" ::: "memory");   // tile0 resident
        __builtin_amdgcn_s_barrier();

        f32x4 acc[8][4] = {};
        bf16x8 af[8][2], bf_[4][2];

        // pre-read af[0..3] of tile 0 (slot 0)
        {
            const char* ab0 = shA + wm * 16384 + lrow * 128;
#pragma unroll
            for (int mi = 0; mi < 4; ++mi) {
                af[mi][0] = *(const bf16x8*)(ab0 + mi * 2048 + kb0);
                af[mi][1] = *(const bf16x8*)(ab0 + mi * 2048 + kb1);
            }
        }

        for (int t = 0; t < NTK; ++t) {
            const int slot  = t & 1;
            const char* ab  = shA + (slot * 2 + wm) * 16384 + lrow * 128;
            const char* bb  = shB + (slot * 2 + (wn >> 1)) * 16384 + ((wn & 1) * 64 + lrow) * 128;
            const char* abN = shA + (((t + 1) & 1) * 2 + wm) * 16384 + lrow * 128;

            // ---- q0: read bfr[0..3]; stage B0_{t+1}; MFMA (mh0,nh0)
#pragma unroll
            for (int ni = 0; ni < 4; ++ni) {
                bf_[ni][0] = *(const bf16x8*)(bb + ni * 2048 + kb0);
                bf_[ni][1] = *(const bf16x8*)(bb + ni * 2048 + kb1);
            }
            stage(t + 1, 2);
            __builtin_amdgcn_s_barrier();
            __builtin_amdgcn_s_setprio(1);
#pragma unroll
            for (int a = 0; a < 4; ++a)
#pragma unroll
                for (int b = 0; b < 2; ++b)
#pragma unroll
                    for (int ks = 0; ks < 2; ++ks)
                        acc[a][b] = __builtin_amdgcn_mfma_f32_16x16x32_bf16(af[a][ks], bf_[b][ks], acc[a][b], 0, 0, 0);
            __builtin_amdgcn_s_setprio(0);
            __builtin_amdgcn_s_barrier();

            // ---- q1: read afr[4..7]; stage B1_{t+1}; MFMA (mh0,nh1)
#pragma unroll
            for (int mi = 4; mi < 8; ++mi) {
                af[mi][0] = *(const bf16x8*)(ab + mi * 2048 + kb0);
                af[mi][1] = *(const bf16x8*)(ab + mi * 2048 + kb1);
            }
            stage(t + 1, 3);
            __builtin_amdgcn_s_barrier();
            __builtin_amdgcn_s_setprio(1);
#pragma unroll
            for (int a = 0; a < 4; ++a)
#pragma unroll
                for (int b = 0; b < 2; ++b)
#pragma unroll
                    for (int ks = 0; ks < 2; ++ks)
                        acc[a][2 + b] = __builtin_amdgcn_mfma_f32_16x16x32_bf16(af[a][ks], bf_[2 + b][ks], acc[a][2 + b], 0, 0, 0);
            __builtin_amdgcn_s_setprio(0);
            __builtin_amdgcn_s_barrier();

            // ---- q2: stage A0_{t+2}; MFMA (mh1,nh0); vmcnt guards q3's prefetch
            stage(t + 2, 0);
            __builtin_amdgcn_s_barrier();
            __builtin_amdgcn_s_setprio(1);
#pragma unroll
            for (int a = 0; a < 4; ++a)
#pragma unroll
                for (int b = 0; b < 2; ++b)
#pragma unroll
                    for (int ks = 0; ks < 2; ++ks)
                        acc[4 + a][b] = __builtin_amdgcn_mfma_f32_16x16x32_bf16(af[4 + a][ks], bf_[b][ks], acc[4 + a][b], 0, 0, 0);
            __builtin_amdgcn_s_setprio(0);
            if (t <= 13)      asm volatile("s_waitcnt vmcnt(6)" ::: "memory"); // A1_{t+1} resident
            else if (t == 14) asm volatile("s_waitcnt vmcnt(4)" ::: "memory");
            __builtin_amdgcn_s_barrier();

            // ---- q3: stage A1_{t+2}; prefetch afr[0..3] of t+1; MFMA (mh1,nh1)
            stage(t + 2, 1);
            if (t + 1 < NTK) {
#pragma unroll
                for (int mi = 0; mi < 4; ++mi) {
                    af[mi][0] = *(const bf16x8*)(abN + mi * 2048 + kb0);
                    af[mi][1] = *(const bf16x8*)(abN + mi * 2048 + kb1);
                }
            }
            __builtin_amdgcn_s_barrier();
            __builtin_amdgcn_s_setprio(1);
#pragma unroll
            for (int a = 0; a < 4; ++a)
#pragma unroll
                for (int b = 0; b < 2; ++b)
#pragma unroll
                    for (int ks = 0; ks < 2; ++ks)
                        acc[4 + a][2 + b] = __builtin_amdgcn_mfma_f32_16x16x32_bf16(af[4 + a][ks], bf_[2 + b][ks], acc[4 + a][2 + b], 0, 0, 0);
            __builtin_amdgcn_s_setprio(0);
            if (t <= 13)      asm volatile("s_waitcnt vmcnt(4)" ::: "memory"); // B_{t+1} resident
            else if (t == 14) asm volatile("s_waitcnt vmcnt(0)" ::: "memory");
            __builtin_amdgcn_s_barrier();
        }

        // ---- epilogue: C/D frag layout col=lane&15, row=(lane>>4)*4+j
        const int crow = (lane >> 4) * 4;
        const int ccol = lane & 15;
        if (MODE == 1) {
#pragma unroll
            for (int mi = 0; mi < 8; ++mi)
#pragma unroll
                for (int ni = 0; ni < 4; ++ni) {
                    size_t gr = row0 + wm * 128 + mi * 16 + crow;
                    size_t gc = colb + wn * 64 + ni * 16 + ccol;
#pragma unroll
                    for (int j = 0; j < 4; ++j)
                        oF[(gr + j) * 1024 + gc] = acc[mi][ni][j];
                }
        } else {
            unsigned short* dst = (p == 0) ? oK : ((p == 1) ? oV : oR);
#pragma unroll
            for (int mi = 0; mi < 8; ++mi)
#pragma unroll
                for (int ni = 0; ni < 4; ++ni) {
                    size_t gr = row0 + wm * 128 + mi * 16 + crow;
                    size_t gc = colb + wn * 64 + ni * 16 + ccol;
#pragma unroll
                    for (int j = 0; j < 4; ++j) {
                        float val = acc[mi][ni][j];
                        if (p == 2) val = 1.0f / (1.0f + __expf(-val));
                        dst[(gr + j) * 1024 + gc] = f2bf(val);
                    }
                }
        }
    }
}

// ---------------- WKV segmented scan (bf16 k,v,r) ----------------
__global__ __launch_bounds__(256) void wkv_phase1(
    const unsigned short* __restrict__ kf, const unsigned short* __restrict__ vf,
    const float* __restrict__ td,
    float* __restrict__ segA, float* __restrict__ segB, float* __restrict__ segP)
{
    const int tid  = blockIdx.x * 256 + threadIdx.x;
    const int lane = tid & 63;
    const int wg   = tid >> 6;
    const int cg   = wg & 63;
    const int s    = wg >> 6;
    const int q    = cg * 64 + lane;
    const int b    = q >> 10;
    const int c    = q & (CDIM - 1);

    const float w = __expf(td[c]);

    float aa = 0.0f, bb = 0.0f, pp = -1e38f;
    size_t idx = (size_t)b * TDIM * CDIM + (size_t)(s * LSEG) * CDIM + c;
#pragma unroll 4
    for (int i = 0; i < LSEG; ++i, idx += CDIM) {
        float kt = bf2f(kf[idx]);
        float vt = bf2f(vf[idx]);
        float ww2 = pp - w;
        float p2  = fmaxf(ww2, kt);
        float e1  = __expf(ww2 - p2);
        float e2  = __expf(kt - p2);
        aa = e1 * aa + e2 * vt;
        bb = e1 * bb + e2;
        pp = p2;
    }
    segA[s * NCH + q] = aa;
    segB[s * NCH + q] = bb;
    segP[s * NCH + q] = pp;
}

__global__ __launch_bounds__(256) void wkv_phase2(
    const float* __restrict__ segA, const float* __restrict__ segB, const float* __restrict__ segP,
    const float* __restrict__ td,
    const float* __restrict__ aa0, const float* __restrict__ bb0, const float* __restrict__ pp0,
    float* __restrict__ preA, float* __restrict__ preB, float* __restrict__ preP,
    float* __restrict__ stout)
{
    const int tid = blockIdx.x * 256 + threadIdx.x;   // 0..NCH-1
    const int c = tid & (CDIM - 1);
    const float w  = __expf(td[c]);
    const float Lw = (float)LSEG * w;

    float aa = aa0[tid], bb = bb0[tid], pp = pp0[tid];
    for (int s = 0; s < SSEG; ++s) {
        preA[s * NCH + tid] = aa;
        preB[s * NCH + tid] = bb;
        preP[s * NCH + tid] = pp;
        float al = segA[s * NCH + tid];
        float bl = segB[s * NCH + tid];
        float pl = segP[s * NCH + tid];
        float ppd = pp - Lw;
        float p  = fmaxf(ppd, pl);
        float e1 = __expf(ppd - p);
        float e2 = __expf(pl - p);
        aa = e1 * aa + e2 * al;
        bb = e1 * bb + e2 * bl;
        pp = p;
    }
    stout[tid]           = aa;
    stout[NCH + tid]     = bb;
    stout[2 * NCH + tid] = pp;
}

__global__ __launch_bounds__(256) void wkv_phase3(
    const unsigned short* __restrict__ kf, const unsigned short* __restrict__ vf,
    const unsigned short* __restrict__ rb,
    const float* __restrict__ td, const float* __restrict__ tf,
    const float* __restrict__ preA, const float* __restrict__ preB, const float* __restrict__ preP,
    unsigned short* __restrict__ rwkvb)
{
    const int tid  = blockIdx.x * 256 + threadIdx.x;
    const int lane = tid & 63;
    const int wg   = tid >> 6;
    const int cg   = wg & 63;
    const int s    = wg >> 6;
    const int q    = cg * 64 + lane;
    const int b    = q >> 10;
    const int c    = q & (CDIM - 1);

    const float w = __expf(td[c]);
    const float u = tf[c];

    float aa = preA[s * NCH + q];
    float bb = preB[s * NCH + q];
    float pp = preP[s * NCH + q];

    size_t idx = (size_t)b * TDIM * CDIM + (size_t)(s * LSEG) * CDIM + c;
#pragma unroll 4
    for (int i = 0; i < LSEG; ++i, idx += CDIM) {
        float kt = bf2f(kf[idx]);
        float vt = bf2f(vf[idx]);
        float rt = bf2f(rb[idx]);
        float ww = u + kt;
        float p  = fmaxf(pp, ww);
        float e1 = __expf(pp - p);
        float e2 = __expf(ww - p);
        float wkv = (e1 * aa + e2 * vt) / (e1 * bb + e2);
        rwkvb[idx] = f2bf(rt * wkv);
        float ww2 = pp - w;
        float p2  = fmaxf(ww2, kt);
        float e1b = __expf(ww2 - p2);
        float e2b = __expf(kt - p2);
        aa = e1b * aa + e2b * vt;
        bb = e1b * bb + e2b;
        pp = p2;
    }
}

extern "C" void kernel_launch(void* const* d_in, const int* in_sizes, int n_in,
                              void* d_out, int out_size, void* d_ws, size_t ws_size,
                              hipStream_t stream) {
    const float* x   = (const float*)d_in[0];
    const float* kw  = (const float*)d_in[1];
    const float* vw  = (const float*)d_in[2];
    const float* rw  = (const float*)d_in[3];
    const float* ow  = (const float*)d_in[4];
    const float* td  = (const float*)d_in[5];
    const float* tf  = (const float*)d_in[6];
    const float* aa0 = (const float*)d_in[7];
    const float* bb0 = (const float*)d_in[8];
    const float* pp0 = (const float*)d_in[9];
    float* out = (float*)d_out;

    char* ws = (char*)d_ws;
    unsigned short* wf    = (unsigned short*)(ws);               //  6,291,456 B  [3072][1024] bf16
    unsigned short* owb   = (unsigned short*)(ws + 6291456);     //  2,097,152 B
    unsigned short* xb    = (unsigned short*)(ws + 8388608);     // 33,554,432 B
    unsigned short* kfb   = (unsigned short*)(ws + 41943040);    // 33,554,432 B
    unsigned short* vfb   = (unsigned short*)(ws + 75497472);    // 33,554,432 B
    unsigned short* rbb   = (unsigned short*)(ws + 109051904);   // 33,554,432 B
    unsigned short* rwkvb = (unsigned short*)(ws + 142606336);   // 33,554,432 B
    float* segA = (float*)(ws + 176160768);
    float* segB = (float*)(ws + 177209344);
    float* segP = (float*)(ws + 178257920);
    float* preA = (float*)(ws + 179306496);
    float* preB = (float*)(ws + 180355072);
    float* preP = (float*)(ws + 181403648);

    hipFuncSetAttribute((const void*)(gemm256<0, 4, 3>), hipFuncAttributeMaxDynamicSharedMemorySize, 131072);
    hipFuncSetAttribute((const void*)(gemm256<1, 4, 1>), hipFuncAttributeMaxDynamicSharedMemorySize, 131072);

    // casts to bf16
    castk<<<2048, 256, 0, stream>>>(x, xb, MDIM * CDIM / 4);
    castw<<<4096, 256, 0, stream>>>(kw, vw, rw, ow, wf, owb);

    // fused QKV projection: 256 blocks (1/CU), 3 projections per block
    gemm256<0, 4, 3><<<256, 512, 131072, stream>>>(xb, wf, kfb, vfb, rbb, nullptr);

    // segmented WKV scan
    wkv_phase1<<<NCH * SSEG / 256, 256, 0, stream>>>(kfb, vfb, td, segA, segB, segP);
    wkv_phase2<<<NCH / 256, 256, 0, stream>>>(segA, segB, segP, td, aa0, bb0, pp0,
                                              preA, preB, preP, out + (size_t)MDIM * CDIM);
    wkv_phase3<<<NCH * SSEG / 256, 256, 0, stream>>>(kfb, vfb, rbb, td, tf,
                                                     preA, preB, preP, rwkvb);

    // output projection: [16384,1024] x [1024,1024]^T -> fp32 d_out, 256 blocks
    gemm256<1, 4, 1><<<256, 512, 131072, stream>>>(rwkvb, owb, nullptr, nullptr, nullptr, out);
}

// Round 11
// 220.356 us; speedup vs baseline: 1.1346x; 1.1346x over previous
//
#include <hip/hip_runtime.h>
#include <stdint.h>

#define BDIM 4
#define TDIM 4096
#define CDIM 1024
#define MDIM (BDIM * TDIM) // 16384
#define SSEG 64            // segments along T
#define LSEG 64            // steps per segment
#define NCH  (BDIM * CDIM) // 4096 channels

#define GK   1024          // GEMM K
#define GK2  2048          // K row stride in bytes (bf16)
#define NTK  16            // K-tiles of 64

typedef __attribute__((ext_vector_type(8))) short bf16x8;
typedef __attribute__((ext_vector_type(4))) float f32x4;

__device__ __forceinline__ unsigned short f2bf(float f) {
    unsigned u = __builtin_bit_cast(unsigned, f);
    u = u + 0x7fffu + ((u >> 16) & 1u); // RNE
    return (unsigned short)(u >> 16);
}
__device__ __forceinline__ float bf2f(unsigned short h) {
    unsigned u = ((unsigned)h) << 16;
    return __builtin_bit_cast(float, u);
}

typedef __attribute__((address_space(1))) const unsigned int g_u32;
typedef __attribute__((address_space(3))) unsigned int l_u32;
__device__ __forceinline__ void gload_lds16(const void* g, void* l) {
    __builtin_amdgcn_global_load_lds((g_u32*)g, (l_u32*)l, 16, 0, 0);
}

// ---------------- all fp32 -> bf16 casts in ONE launch ----------------
// x: 16M elems (4M float4), weights: 4 x 1M elems (262144 float4 each).
// grid covers 4M + 4*262144 = 5,242,880 float4 chunks at 256 thr/blk.
__global__ void castall(const float* __restrict__ x,
                        const float* __restrict__ kw, const float* __restrict__ vw,
                        const float* __restrict__ rw, const float* __restrict__ ow,
                        unsigned short* __restrict__ xb,
                        unsigned short* __restrict__ wf, unsigned short* __restrict__ owb) {
    int i = blockIdx.x * 256 + threadIdx.x;
    const float* s;
    unsigned short* d;
    int j;
    if (i < 4194304) {                       // x
        s = x; d = xb; j = i;
    } else {
        int k = i - 4194304;
        int m = k >> 18; j = k & 262143;     // which weight
        s = (m == 0) ? kw : (m == 1) ? vw : (m == 2) ? rw : ow;
        d = (m < 3) ? (wf + (size_t)m * 1048576) : owb;
    }
    float4 f = ((const float4*)s)[j];
    ushort4 o;
    o.x = f2bf(f.x); o.y = f2bf(f.y); o.z = f2bf(f.z); o.w = f2bf(f.w);
    ((ushort4*)d)[j] = o;
}

// ---------------- 256x256 bf16 GEMM, 2 merged phases per K-tile -------------
// Round-5 verified geometry (16x16x32 MFMA, XOR swizzle both-sides, counted
// vmcnt, intrinsic barriers, L2-locality XCD swizzle) with q0+q1 and q2+q3
// merged: per K-tile only 4 barriers + 2 vmcnt(4) for 64 MFMA/wave.
//  P0: read bf_[0..3] + af[4..7] (16 ds_read); stage B0,B1(t+1); barrier;
//      32 MFMA (mh0 x all n); vmcnt(4) [A(t+1) resident]; barrier.
//  P1: prefetch af[0..3] of t+1 (other slot); stage A0,A1(t+2); barrier;
//      32 MFMA (mh1 x all n); vmcnt(4) [B(t+1) resident]; barrier.
// Hazards: every stage->read / read->overwrite pair is >= 1 barrier apart
// (same margins as the verified round-5 ledger). Tail: t=14 -> (4,0).
// MODE 0: fused QKV epilogue -> oK/oV(bf16), oR(sigmoid,bf16). MODE 1: fp32.
template <int MODE, int NT>
__global__ __launch_bounds__(512, 2) void gemm256(
    const unsigned short* __restrict__ A,
    const unsigned short* __restrict__ Bw,
    unsigned short* __restrict__ oK, unsigned short* __restrict__ oV,
    unsigned short* __restrict__ oR, float* __restrict__ oF)
{
    extern __shared__ char sh[];
    char* shA = sh;             // 2 slots x 2 halves x 16384 B
    char* shB = sh + 65536;

    const int tid  = threadIdx.x;
    const int wave = tid >> 6;
    const int lane = tid & 63;
    const int wm   = wave >> 2;      // 0..1 (M half)
    const int wn   = wave & 3;       // 0..3 (N quarter)
    const int lrow = lane & 15;
    const int koct = lane >> 4;      // 0..3

    // per-thread-constant swizzled k-offsets for LDS reads
    const int kb0 = (koct * 16) ^ ((lrow & 7) << 4);
    const int kb1 = kb0 ^ 64;

    // per-thread-constant stage offsets (2 chunks of 16B per stage call)
    const int sr0  = tid >> 3;                 // row of chunk 0 (0..63)
    const int sc0  = ((tid & 7) * 16) ^ ((sr0 & 7) << 4);
    const int sr1  = (512 + tid) >> 3;         // row of chunk 1 (64..127)
    const int sc1  = ((tid & 7) * 16) ^ ((sr1 & 7) << 4);
    const int sd0  = tid * 16;
    const int sd1  = 8192 + tid * 16;

    // L2-locality XCD swizzle (grid = 8 * 8 * NT blocks)
    const int bid = blockIdx.x;
    const int xcd = bid & 7;
    const int idx = bid >> 3;
    const int mt  = xcd * 8 + idx / NT;  // disjoint A-slice per XCD
    const int nt  = idx % NT;            // nt-fast: A panel L2-reused
    const size_t row0 = (size_t)mt * 256;
    const size_t col0 = (size_t)nt * 256;

    const char* gA = (const char*)A  + row0 * GK2;
    const char* gB = (const char*)Bw + col0 * GK2;

    // stage one half-tile of tile tt; part: 0=A h0, 1=A h1, 2=B h0, 3=B h1
    auto stage = [&](int tt, int part) {
        if (tt >= NTK) return;
        int slot = tt & 1;
        int isA  = (part < 2) ? 1 : 0;
        int half = part & 1;
        const char* gbase = (isA ? gA : gB) + (size_t)half * 128 * GK2 + tt * 128;
        char* lbase = (isA ? shA : shB) + (slot * 2 + half) * 16384;
        gload_lds16(gbase + (size_t)sr0 * GK2 + sc0, lbase + sd0);
        gload_lds16(gbase + (size_t)sr1 * GK2 + sc1, lbase + sd1);
    };

    // prologue: tile0 (A0,A1,B0,B1) + tile1 (A0,A1) = 6 halves (12 loads)
    stage(0, 0); stage(0, 1); stage(0, 2); stage(0, 3);
    stage(1, 0); stage(1, 1);
    asm volatile("s_waitcnt vmcnt(4)" ::: "memory");   // tile0 fully resident
    __builtin_amdgcn_s_barrier();

    f32x4 acc[8][4] = {};
    bf16x8 af[8][2], bf_[4][2];

    // pre-read af[0..3] of tile 0 (slot 0)
    {
        const char* ab0 = shA + wm * 16384 + lrow * 128;
#pragma unroll
        for (int mi = 0; mi < 4; ++mi) {
            af[mi][0] = *(const bf16x8*)(ab0 + mi * 2048 + kb0);
            af[mi][1] = *(const bf16x8*)(ab0 + mi * 2048 + kb1);
        }
    }

    for (int t = 0; t < NTK; ++t) {
        const int slot  = t & 1;
        const char* ab  = shA + (slot * 2 + wm) * 16384 + lrow * 128;
        const char* bb  = shB + (slot * 2 + (wn >> 1)) * 16384 + ((wn & 1) * 64 + lrow) * 128;
        const char* abN = shA + (((t + 1) & 1) * 2 + wm) * 16384 + lrow * 128;

        // ==== P0: read bf_[0..3] + af[4..7]; stage B0,B1(t+1); 32 MFMA (mh0)
#pragma unroll
        for (int ni = 0; ni < 4; ++ni) {
            bf_[ni][0] = *(const bf16x8*)(bb + ni * 2048 + kb0);
            bf_[ni][1] = *(const bf16x8*)(bb + ni * 2048 + kb1);
        }
#pragma unroll
        for (int mi = 4; mi < 8; ++mi) {
            af[mi][0] = *(const bf16x8*)(ab + mi * 2048 + kb0);
            af[mi][1] = *(const bf16x8*)(ab + mi * 2048 + kb1);
        }
        stage(t + 1, 2);
        stage(t + 1, 3);
        __builtin_amdgcn_s_barrier();
        __builtin_amdgcn_s_setprio(1);
#pragma unroll
        for (int a = 0; a < 4; ++a)
#pragma unroll
            for (int b = 0; b < 4; ++b)
#pragma unroll
                for (int ks = 0; ks < 2; ++ks)
                    acc[a][b] = __builtin_amdgcn_mfma_f32_16x16x32_bf16(af[a][ks], bf_[b][ks], acc[a][b], 0, 0, 0);
        __builtin_amdgcn_s_setprio(0);
        if (t <= 14)      asm volatile("s_waitcnt vmcnt(4)" ::: "memory"); // A(t+1) resident
        __builtin_amdgcn_s_barrier();

        // ==== P1: prefetch af[0..3](t+1); stage A0,A1(t+2); 32 MFMA (mh1)
        if (t + 1 < NTK) {
#pragma unroll
            for (int mi = 0; mi < 4; ++mi) {
                af[mi][0] = *(const bf16x8*)(abN + mi * 2048 + kb0);
                af[mi][1] = *(const bf16x8*)(abN + mi * 2048 + kb1);
            }
        }
        stage(t + 2, 0);
        stage(t + 2, 1);
        __builtin_amdgcn_s_barrier();
        __builtin_amdgcn_s_setprio(1);
#pragma unroll
        for (int a = 0; a < 4; ++a)
#pragma unroll
            for (int b = 0; b < 4; ++b)
#pragma unroll
                for (int ks = 0; ks < 2; ++ks)
                    acc[4 + a][b] = __builtin_amdgcn_mfma_f32_16x16x32_bf16(af[4 + a][ks], bf_[b][ks], acc[4 + a][b], 0, 0, 0);
        __builtin_amdgcn_s_setprio(0);
        if (t <= 13)      asm volatile("s_waitcnt vmcnt(4)" ::: "memory"); // B(t+1) resident
        else if (t == 14) asm volatile("s_waitcnt vmcnt(0)" ::: "memory");
        __builtin_amdgcn_s_barrier();
    }

    // ---- epilogue: C/D frag layout col=lane&15, row=(lane>>4)*4+j
    const int crow = (lane >> 4) * 4;
    const int ccol = lane & 15;
    if (MODE == 1) {
#pragma unroll
        for (int mi = 0; mi < 8; ++mi)
#pragma unroll
            for (int ni = 0; ni < 4; ++ni) {
                size_t gr = row0 + wm * 128 + mi * 16 + crow;
                size_t gc = col0 + wn * 64 + ni * 16 + ccol;
#pragma unroll
                for (int j = 0; j < 4; ++j)
                    oF[(gr + j) * 1024 + gc] = acc[mi][ni][j];
            }
    } else {
        const int region = nt >> 2;  // 0=K, 1=V, 2=R
        unsigned short* dst = (region == 0) ? oK : ((region == 1) ? oV : oR);
        const size_t cb0 = (size_t)(nt & 3) * 256;
#pragma unroll
        for (int mi = 0; mi < 8; ++mi)
#pragma unroll
            for (int ni = 0; ni < 4; ++ni) {
                size_t gr = row0 + wm * 128 + mi * 16 + crow;
                size_t gc = cb0 + wn * 64 + ni * 16 + ccol;
#pragma unroll
                for (int j = 0; j < 4; ++j) {
                    float val = acc[mi][ni][j];
                    if (region == 2) val = 1.0f / (1.0f + __expf(-val));
                    dst[(gr + j) * 1024 + gc] = f2bf(val);
                }
            }
    }
}

// ---------------- WKV segmented scan (bf16 k,v,r) ----------------
__global__ __launch_bounds__(256) void wkv_phase1(
    const unsigned short* __restrict__ kf, const unsigned short* __restrict__ vf,
    const float* __restrict__ td,
    float* __restrict__ segA, float* __restrict__ segB, float* __restrict__ segP)
{
    const int tid  = blockIdx.x * 256 + threadIdx.x;
    const int lane = tid & 63;
    const int wg   = tid >> 6;
    const int cg   = wg & 63;
    const int s    = wg >> 6;
    const int q    = cg * 64 + lane;
    const int b    = q >> 10;
    const int c    = q & (CDIM - 1);

    const float w = __expf(td[c]);

    float aa = 0.0f, bb = 0.0f, pp = -1e38f;
    size_t idx = (size_t)b * TDIM * CDIM + (size_t)(s * LSEG) * CDIM + c;
#pragma unroll 4
    for (int i = 0; i < LSEG; ++i, idx += CDIM) {
        float kt = bf2f(kf[idx]);
        float vt = bf2f(vf[idx]);
        float ww2 = pp - w;
        float p2  = fmaxf(ww2, kt);
        float e1  = __expf(ww2 - p2);
        float e2  = __expf(kt - p2);
        aa = e1 * aa + e2 * vt;
        bb = e1 * bb + e2;
        pp = p2;
    }
    segA[s * NCH + q] = aa;
    segB[s * NCH + q] = bb;
    segP[s * NCH + q] = pp;
}

__global__ __launch_bounds__(256) void wkv_phase2(
    const float* __restrict__ segA, const float* __restrict__ segB, const float* __restrict__ segP,
    const float* __restrict__ td,
    const float* __restrict__ aa0, const float* __restrict__ bb0, const float* __restrict__ pp0,
    float* __restrict__ preA, float* __restrict__ preB, float* __restrict__ preP,
    float* __restrict__ stout)
{
    const int tid = blockIdx.x * 256 + threadIdx.x;   // 0..NCH-1
    const int c = tid & (CDIM - 1);
    const float w  = __expf(td[c]);
    const float Lw = (float)LSEG * w;

    float aa = aa0[tid], bb = bb0[tid], pp = pp0[tid];
    for (int s = 0; s < SSEG; ++s) {
        preA[s * NCH + tid] = aa;
        preB[s * NCH + tid] = bb;
        preP[s * NCH + tid] = pp;
        float al = segA[s * NCH + tid];
        float bl = segB[s * NCH + tid];
        float pl = segP[s * NCH + tid];
        float ppd = pp - Lw;
        float p  = fmaxf(ppd, pl);
        float e1 = __expf(ppd - p);
        float e2 = __expf(pl - p);
        aa = e1 * aa + e2 * al;
        bb = e1 * bb + e2 * bl;
        pp = p;
    }
    stout[tid]           = aa;
    stout[NCH + tid]     = bb;
    stout[2 * NCH + tid] = pp;
}

__global__ __launch_bounds__(256) void wkv_phase3(
    const unsigned short* __restrict__ kf, const unsigned short* __restrict__ vf,
    const unsigned short* __restrict__ rb,
    const float* __restrict__ td, const float* __restrict__ tf,
    const float* __restrict__ preA, const float* __restrict__ preB, const float* __restrict__ preP,
    unsigned short* __restrict__ rwkvb)
{
    const int tid  = blockIdx.x * 256 + threadIdx.x;
    const int lane = tid & 63;
    const int wg   = tid >> 6;
    const int cg   = wg & 63;
    const int s    = wg >> 6;
    const int q    = cg * 64 + lane;
    const int b    = q >> 10;
    const int c    = q & (CDIM - 1);

    const float w = __expf(td[c]);
    const float u = tf[c];

    float aa = preA[s * NCH + q];
    float bb = preB[s * NCH + q];
    float pp = preP[s * NCH + q];

    size_t idx = (size_t)b * TDIM * CDIM + (size_t)(s * LSEG) * CDIM + c;
#pragma unroll 4
    for (int i = 0; i < LSEG; ++i, idx += CDIM) {
        float kt = bf2f(kf[idx]);
        float vt = bf2f(vf[idx]);
        float rt = bf2f(rb[idx]);
        float ww = u + kt;
        float p  = fmaxf(pp, ww);
        float e1 = __expf(pp - p);
        float e2 = __expf(ww - p);
        float wkv = (e1 * aa + e2 * vt) / (e1 * bb + e2);
        rwkvb[idx] = f2bf(rt * wkv);
        float ww2 = pp - w;
        float p2  = fmaxf(ww2, kt);
        float e1b = __expf(ww2 - p2);
        float e2b = __expf(kt - p2);
        aa = e1b * aa + e2b * vt;
        bb = e1b * bb + e2b;
        pp = p2;
    }
}

extern "C" void kernel_launch(void* const* d_in, const int* in_sizes, int n_in,
                              void* d_out, int out_size, void* d_ws, size_t ws_size,
                              hipStream_t stream) {
    const float* x   = (const float*)d_in[0];
    const float* kw  = (const float*)d_in[1];
    const float* vw  = (const float*)d_in[2];
    const float* rw  = (const float*)d_in[3];
    const float* ow  = (const float*)d_in[4];
    const float* td  = (const float*)d_in[5];
    const float* tf  = (const float*)d_in[6];
    const float* aa0 = (const float*)d_in[7];
    const float* bb0 = (const float*)d_in[8];
    const float* pp0 = (const float*)d_in[9];
    float* out = (float*)d_out;

    char* ws = (char*)d_ws;
    unsigned short* wf    = (unsigned short*)(ws);               //  6,291,456 B  [3072][1024] bf16
    unsigned short* owb   = (unsigned short*)(ws + 6291456);     //  2,097,152 B
    unsigned short* xb    = (unsigned short*)(ws + 8388608);     // 33,554,432 B
    unsigned short* kfb   = (unsigned short*)(ws + 41943040);    // 33,554,432 B
    unsigned short* vfb   = (unsigned short*)(ws + 75497472);    // 33,554,432 B
    unsigned short* rbb   = (unsigned short*)(ws + 109051904);   // 33,554,432 B
    unsigned short* rwkvb = (unsigned short*)(ws + 142606336);   // 33,554,432 B
    float* segA = (float*)(ws + 176160768);
    float* segB = (float*)(ws + 177209344);
    float* segP = (float*)(ws + 178257920);
    float* preA = (float*)(ws + 179306496);
    float* preB = (float*)(ws + 180355072);
    float* preP = (float*)(ws + 181403648);

    hipFuncSetAttribute((const void*)(gemm256<0, 12>), hipFuncAttributeMaxDynamicSharedMemorySize, 131072);
    hipFuncSetAttribute((const void*)(gemm256<1, 4>),  hipFuncAttributeMaxDynamicSharedMemorySize, 131072);

    // all casts in one launch: 4M (x) + 1M (weights) float4 chunks
    castall<<<20480, 256, 0, stream>>>(x, kw, vw, rw, ow, xb, wf, owb);

    // fused QKV projection: [16384,1024] x [3072,1024]^T, 768 blocks
    gemm256<0, 12><<<768, 512, 131072, stream>>>(xb, wf, kfb, vfb, rbb, nullptr);

    // segmented WKV scan
    wkv_phase1<<<NCH * SSEG / 256, 256, 0, stream>>>(kfb, vfb, td, segA, segB, segP);
    wkv_phase2<<<NCH / 256, 256, 0, stream>>>(segA, segB, segP, td, aa0, bb0, pp0,
                                              preA, preB, preP, out + (size_t)MDIM * CDIM);
    wkv_phase3<<<NCH * SSEG / 256, 256, 0, stream>>>(kfb, vfb, rbb, td, tf,
                                                     preA, preB, preP, rwkvb);

    // output projection: [16384,1024] x [1024,1024]^T -> fp32 d_out, 256 blocks
    gemm256<1, 4><<<256, 512, 131072, stream>>>(rwkvb, owb, nullptr, nullptr, nullptr, out);
}